// Round 7
// baseline (149.606 us; speedup 1.0000x reference)
//
#include <hip/hip_runtime.h>
#include <math.h>

#define BB      256
#define GG      4096
#define DG      256
#define DH      256
#define DZ      64
#define NGENES  30000
#define KPAD    30016            // NGENES padded to multiple of 32
#define NCHUNK  (KPAD / 32)      // 938 K-chunks of 32
#define KSPLIT  128
#define RED     16               // splits combined per stage-1 reduce block
#define NPART2  (KSPLIT / RED)   // 8
#define HALF    (KPAD / 2)       // 15008
#define FB_TILES (NCHUNK * 16)   // 15008 fragment tiles of 1 KB
// fallback (R3) path
#define SPLIT   4
#define GCHUNK  (GG / SPLIT)

typedef __attribute__((ext_vector_type(8))) short  short8v;
typedef __attribute__((ext_vector_type(4))) float  floatx4;

__device__ __forceinline__ unsigned short bf16_rn(float f) {
    unsigned u = __float_as_uint(f);
    u += 0x7FFFu + ((u >> 16) & 1u);   // round-to-nearest-even
    return (unsigned short)(u >> 16);
}

// ---------------------------------------------------------------------------
// Scatter: W16[b, idx] += log1p(x), output bf16.  grid (B, 2).
// ---------------------------------------------------------------------------
__global__ __launch_bounds__(256) void scatter_kernel(
    const float* __restrict__ x,
    const int*   __restrict__ gi,
    unsigned short* __restrict__ W16,  // (BB, KPAD) bf16
    float* __restrict__ wsum,          // (BB)
    float* __restrict__ xsum)          // (BB)
{
    const int b   = blockIdx.x;
    const int h   = blockIdx.y;
    const int tid = threadIdx.x;
    const int base = h * HALF;

    __shared__ float sW[HALF];
    for (int i = tid; i < HALF; i += 256) sW[i] = 0.f;
    __syncthreads();

    const float4* x4 = (const float4*)(x  + (size_t)b * GG);
    const int4*   g4 = (const int4*)  (gi + (size_t)b * GG);

    float lws = 0.f, xs = 0.f;
    #pragma unroll
    for (int it = 0; it < 4; ++it) {
        const int    e  = it * 256 + tid;
        const float4 xv = x4[e];
        const int4   iv = g4[e];
        const float lw0 = log1pf(xv.x), lw1 = log1pf(xv.y);
        const float lw2 = log1pf(xv.z), lw3 = log1pf(xv.w);
        lws += lw0 + lw1 + lw2 + lw3;
        xs  += xv.x + xv.y + xv.z + xv.w;
        int r0 = iv.x - base, r1 = iv.y - base, r2 = iv.z - base, r3 = iv.w - base;
        if ((unsigned)r0 < (unsigned)HALF) atomicAdd(&sW[r0], lw0);
        if ((unsigned)r1 < (unsigned)HALF) atomicAdd(&sW[r1], lw1);
        if ((unsigned)r2 < (unsigned)HALF) atomicAdd(&sW[r2], lw2);
        if ((unsigned)r3 < (unsigned)HALF) atomicAdd(&sW[r3], lw3);
    }
    __syncthreads();

    uint4* dst = (uint4*)(W16 + (size_t)b * KPAD + base);
    for (int i = tid; i < HALF / 8; i += 256) {
        const float* s = &sW[i * 8];
        uint4 o;
        o.x = (unsigned)bf16_rn(s[0]) | ((unsigned)bf16_rn(s[1]) << 16);
        o.y = (unsigned)bf16_rn(s[2]) | ((unsigned)bf16_rn(s[3]) << 16);
        o.z = (unsigned)bf16_rn(s[4]) | ((unsigned)bf16_rn(s[5]) << 16);
        o.w = (unsigned)bf16_rn(s[6]) | ((unsigned)bf16_rn(s[7]) << 16);
        dst[i] = o;
    }
    __syncthreads();   // all reads of sW done; safe to reuse sW[0..7]

    #pragma unroll
    for (int off = 32; off > 0; off >>= 1) {
        lws += __shfl_down(lws, off);
        xs  += __shfl_down(xs,  off);
    }
    if ((tid & 63) == 0) { sW[tid >> 6] = lws; sW[4 + (tid >> 6)] = xs; }
    __syncthreads();
    if (tid == 0 && h == 0) {
        wsum[b] = sW[0] + sW[1] + sW[2] + sW[3];
        xsum[b] = sW[4] + sW[5] + sW[6] + sW[7];
    }
}

// ---------------------------------------------------------------------------
// fragB: emb fp32 (NGENES,256) -> bf16 in MFMA B-fragment order.
// ---------------------------------------------------------------------------
__global__ __launch_bounds__(256) void fragb_kernel(
    const float* __restrict__ emb, unsigned short* __restrict__ fragB)
{
    const int tile = blockIdx.x * 4 + (threadIdx.x >> 6);
    const int lane = threadIdx.x & 63;
    const int kc = tile >> 4;
    const int nt = tile & 15;
    const int n  = (nt << 4) + (lane & 15);
    const int k0 = (kc << 5) + ((lane >> 4) << 3);

    unsigned short v[8] __attribute__((aligned(16)));
    #pragma unroll
    for (int j = 0; j < 8; ++j) {
        const int k = k0 + j;
        v[j] = (k < NGENES) ? bf16_rn(emb[(size_t)k * DG + n]) : (unsigned short)0;
    }
    *(uint4*)(fragB + (size_t)tile * 512 + lane * 8) = *(const uint4*)v;
}

// ---------------------------------------------------------------------------
// GEMM: h_pool_partial = W16 (256 x KPAD bf16) @ fragB -> bf16 partials.
// grid (4 Mtiles, KSPLIT=128) = 512 blocks.  Double-buffered B staging
// (one barrier per chunk, loads in flight across MFMA), LDS-transposed
// bf16 epilogue (8 coalesced dwordx4 stores per lane).
// Partials: wsg16[(m*KSPLIT + ks)*256 + n], bf16.
// ---------------------------------------------------------------------------
__global__ __launch_bounds__(256) void gemm_kernel(
    const unsigned short* __restrict__ W16,
    const unsigned short* __restrict__ fragB,
    unsigned short* __restrict__ wsg16)
{
    const int mt   = blockIdx.x;
    const int ks   = blockIdx.y;
    const int tid  = threadIdx.x;
    const int w    = tid >> 6;
    const int lane = tid & 63;
    const int quad = lane >> 4;
    const int l16  = lane & 15;

    const int q = NCHUNK / KSPLIT;           // 7
    const int r = NCHUNK % KSPLIT;           // 42
    const int c0  = ks * q + (ks < r ? ks : r);
    const int cnt = q + (ks < r ? 1 : 0);

    __shared__ short8v sB[2][1024];          // 32 KB, double-buffered

    const unsigned short* Arow =
        W16 + (size_t)((mt << 6) + (w << 4) + l16) * KPAD + (quad << 3);

    floatx4 acc[16];
    #pragma unroll
    for (int nt = 0; nt < 16; ++nt) acc[nt] = (floatx4){0.f, 0.f, 0.f, 0.f};

    // prologue: stage chunk c0 into buffer 0
    uint4 breg[4];
    {
        const uint4* src = (const uint4*)(fragB + (size_t)c0 * 8192);
        #pragma unroll
        for (int i = 0; i < 4; ++i) breg[i] = src[i * 256 + tid];
    }
    short8v af = *(const short8v*)(Arow + ((size_t)c0 << 5));
    #pragma unroll
    for (int i = 0; i < 4; ++i) ((uint4*)sB[0])[i * 256 + tid] = breg[i];
    __syncthreads();

    for (int c = 0; c < cnt; ++c) {
        const int cur = c & 1;
        short8v afn;
        if (c + 1 < cnt) {   // issue next-chunk global loads (stay in flight)
            const uint4* src = (const uint4*)(fragB + (size_t)(c0 + c + 1) * 8192);
            #pragma unroll
            for (int i = 0; i < 4; ++i) breg[i] = src[i * 256 + tid];
            afn = *(const short8v*)(Arow + ((size_t)(c0 + c + 1) << 5));
        }
        #pragma unroll
        for (int nt = 0; nt < 16; ++nt) {
            const short8v bf = sB[cur][nt * 64 + lane];
            acc[nt] = __builtin_amdgcn_mfma_f32_16x16x32_bf16(af, bf, acc[nt], 0, 0, 0);
        }
        if (c + 1 < cnt) {
            #pragma unroll
            for (int i = 0; i < 4; ++i) ((uint4*)sB[cur ^ 1])[i * 256 + tid] = breg[i];
            af = afn;
        }
        __syncthreads();
    }

    // epilogue: per-wave LDS transpose to bf16, then coalesced 16 B stores.
    // (sB is dead for all waves after the barrier above; alias 8 KB per wave)
    unsigned short* epi = (unsigned short*)sB + (w << 12);   // 4096 ushorts
    #pragma unroll
    for (int nt = 0; nt < 16; ++nt) {
        #pragma unroll
        for (int reg = 0; reg < 4; ++reg)
            epi[((quad << 2) + reg) * 256 + (nt << 4) + l16] = bf16_rn(acc[nt][reg]);
    }
    // wave-local dependency; compiler inserts lgkm wait
    uint4* wrow = (uint4*)wsg16;
    #pragma unroll
    for (int j = 0; j < 8; ++j) {
        const int flat = lane + (j << 6);    // 0..511
        const int rr   = flat >> 5;          // row 0..15
        const int u    = flat & 31;          // uint4 index within row
        const uint4 v  = *(const uint4*)(epi + rr * 256 + (u << 3));
        const int m    = (mt << 6) + (w << 4) + rr;
        wrow[(((size_t)m * KSPLIT + ks) << 5) + u] = v;
    }
}

// ---------------------------------------------------------------------------
// Stage-1 reduce: 128 bf16 partials -> 8 fp32.  grid (BB, NPART2), 256 thr.
// Block (b,p) reads a contiguous 8 KB chunk (16 rows x 512 B), unrolled.
// ---------------------------------------------------------------------------
__global__ __launch_bounds__(256) void reduce_kernel(
    const unsigned short* __restrict__ wsg16, float* __restrict__ part2)
{
    const int b = blockIdx.x, p = blockIdx.y, d = threadIdx.x;
    const unsigned short* src = wsg16 + ((size_t)b * KSPLIT + p * RED) * DG + d;
    float s = 0.f;
    #pragma unroll
    for (int i = 0; i < RED; ++i)
        s += __uint_as_float((unsigned)src[(size_t)i * DG] << 16);
    part2[((size_t)b * NPART2 + p) * DG + d] = s;
}

// ---------------------------------------------------------------------------
// Fallback R3 kernels (used only if ws_size too small for the GEMM path)
// ---------------------------------------------------------------------------
__global__ __launch_bounds__(256) void convert_kernel(
    const float* __restrict__ emb, unsigned short* __restrict__ embh, int n4)
{
    const float4* e4 = (const float4*)emb;
    ushort4*      o4 = (ushort4*)embh;
    const int stride = gridDim.x * 256;
    for (int i = blockIdx.x * 256 + threadIdx.x; i < n4; i += stride) {
        const float4 v = e4[i];
        ushort4 o;
        o.x = bf16_rn(v.x); o.y = bf16_rn(v.y);
        o.z = bf16_rn(v.z); o.w = bf16_rn(v.w);
        o4[i] = o;
    }
}

__global__ __launch_bounds__(256) void pool_bf16_kernel(
    const float*          __restrict__ x,
    const int*            __restrict__ gi,
    const unsigned short* __restrict__ embh,
    float* __restrict__ ws_pool,
    float* __restrict__ ws_wsum,
    float* __restrict__ ws_xsum)
{
    const int b    = blockIdx.x;
    const int s    = blockIdx.y;
    const int tid  = threadIdx.x;
    const int wave = tid >> 6;
    const int lane = tid & 63;

    const float* xrow = x  + (size_t)b * GG + (size_t)s * GCHUNK;
    const int*   irow = gi + (size_t)b * GG + (size_t)s * GCHUNK;
    const uint2* emb2 = (const uint2*)embh;

    __shared__ float lw_s[256];
    __shared__ int   idx_s[256];
    __shared__ float accred[4][256];
    __shared__ float redw[4], redx[4];

    float wsum = 0.f, xsum = 0.f;
    float4 acc = make_float4(0.f, 0.f, 0.f, 0.f);

    for (int g0 = 0; g0 < GCHUNK; g0 += 256) {
        __syncthreads();
        const float xv = xrow[g0 + tid];
        const int   iv = irow[g0 + tid];
        const float lw = log1pf(xv);
        xsum += xv;
        wsum += lw;
        lw_s[tid]  = lw;
        idx_s[tid] = iv;
        __syncthreads();

        #pragma unroll 8
        for (int k = 0; k < 64; ++k) {
            const int   gidx = (k << 2) | wave;
            const float lw_b = lw_s[gidx];
            const uint2 e    = emb2[(size_t)idx_s[gidx] * 64 + lane];
            acc.x = fmaf(lw_b, __uint_as_float(e.x << 16),         acc.x);
            acc.y = fmaf(lw_b, __uint_as_float(e.x & 0xFFFF0000u), acc.y);
            acc.z = fmaf(lw_b, __uint_as_float(e.y << 16),         acc.z);
            acc.w = fmaf(lw_b, __uint_as_float(e.y & 0xFFFF0000u), acc.w);
        }
    }

    accred[wave][lane * 4 + 0] = acc.x;
    accred[wave][lane * 4 + 1] = acc.y;
    accred[wave][lane * 4 + 2] = acc.z;
    accred[wave][lane * 4 + 3] = acc.w;

    #pragma unroll
    for (int off = 32; off > 0; off >>= 1) {
        wsum += __shfl_down(wsum, off);
        xsum += __shfl_down(xsum, off);
    }
    if (lane == 0) { redw[wave] = wsum; redx[wave] = xsum; }
    __syncthreads();

    const float tot = accred[0][tid] + accred[1][tid] + accred[2][tid] + accred[3][tid];
    ws_pool[((size_t)b * SPLIT + s) * DG + tid] = tot;
    if (tid == 0) {
        ws_wsum[b * SPLIT + s] = redw[0] + redw[1] + redw[2] + redw[3];
        ws_xsum[b * SPLIT + s] = redx[0] + redx[1] + redx[2] + redx[3];
    }
}

// ---------------------------------------------------------------------------
// MLP: combine NS partials (compile-time, unrolled) + normalize + 3-layer
// head.  One block (512 thr) per row.
// out: mu (B*64) | logvar (B*64) | h_pool (B*256)
// ---------------------------------------------------------------------------
template <int NS, int NW>
__global__ __launch_bounds__(512) void mlp_kernel(
    const float* __restrict__ part,
    const float* __restrict__ wsA, const float* __restrict__ xsA,
    const float* __restrict__ W1, const float* __restrict__ b1,
    const float* __restrict__ W2, const float* __restrict__ b2,
    const float* __restrict__ Wmu, const float* __restrict__ bmu,
    const float* __restrict__ Wlv, const float* __restrict__ blv,
    float* __restrict__ out)
{
    const int b   = blockIdx.x;
    const int tid = threadIdx.x;
    const int kq  = tid >> 6;
    const int c4  = tid & 63;

    __shared__ float  h[DH + 1];
    __shared__ float  h1[DH];
    __shared__ float  h2[DH];
    __shared__ float4 red[8][64];
    __shared__ float  redz[8][64];

    if (tid < DH) {
        float acc = 0.f;
        #pragma unroll
        for (int s = 0; s < NS; ++s)
            acc += part[((size_t)b * NS + s) * DG + tid];
        float wsum = 0.f, xsum = 0.f;
        #pragma unroll
        for (int s = 0; s < NW; ++s) {
            wsum += wsA[b * NW + s];
            xsum += xsA[b * NW + s];
        }
        const float hp = acc / (wsum + 1e-8f);
        out[2 * BB * DZ + (size_t)b * DG + tid] = hp;
        h[tid] = hp;
        if (tid == 0) h[DH] = log1pf(xsum);
    }
    __syncthreads();

    {   // layer 1: (257) @ W1(257,256), relu
        const float4* Wv = (const float4*)W1;
        float4 a = make_float4(0.f, 0.f, 0.f, 0.f);
        const int i0 = kq * 32;
        const int i1 = i0 + 32 + (kq == 7 ? 1 : 0);
        for (int i = i0; i < i1; ++i) {
            const float  hi = h[i];
            const float4 w  = Wv[(size_t)i * 64 + c4];
            a.x = fmaf(hi, w.x, a.x);
            a.y = fmaf(hi, w.y, a.y);
            a.z = fmaf(hi, w.z, a.z);
            a.w = fmaf(hi, w.w, a.w);
        }
        red[kq][c4] = a;
        __syncthreads();
        if (tid < 64) {
            float4 t = red[0][tid];
            #pragma unroll
            for (int s = 1; s < 8; ++s) {
                const float4 rr = red[s][tid];
                t.x += rr.x; t.y += rr.y; t.z += rr.z; t.w += rr.w;
            }
            const float4 bb = ((const float4*)b1)[tid];
            h1[4 * tid + 0] = fmaxf(t.x + bb.x, 0.f);
            h1[4 * tid + 1] = fmaxf(t.y + bb.y, 0.f);
            h1[4 * tid + 2] = fmaxf(t.z + bb.z, 0.f);
            h1[4 * tid + 3] = fmaxf(t.w + bb.w, 0.f);
        }
        __syncthreads();
    }

    {   // layer 2: (256) @ W2(256,256), relu
        const float4* Wv = (const float4*)W2;
        float4 a = make_float4(0.f, 0.f, 0.f, 0.f);
        const int i0 = kq * 32;
        for (int i = i0; i < i0 + 32; ++i) {
            const float  hi = h1[i];
            const float4 w  = Wv[(size_t)i * 64 + c4];
            a.x = fmaf(hi, w.x, a.x);
            a.y = fmaf(hi, w.y, a.y);
            a.z = fmaf(hi, w.z, a.z);
            a.w = fmaf(hi, w.w, a.w);
        }
        red[kq][c4] = a;
        __syncthreads();
        if (tid < 64) {
            float4 t = red[0][tid];
            #pragma unroll
            for (int s = 1; s < 8; ++s) {
                const float4 rr = red[s][tid];
                t.x += rr.x; t.y += rr.y; t.z += rr.z; t.w += rr.w;
            }
            const float4 bb = ((const float4*)b2)[tid];
            h2[4 * tid + 0] = fmaxf(t.x + bb.x, 0.f);
            h2[4 * tid + 1] = fmaxf(t.y + bb.y, 0.f);
            h2[4 * tid + 2] = fmaxf(t.z + bb.z, 0.f);
            h2[4 * tid + 3] = fmaxf(t.w + bb.w, 0.f);
        }
        __syncthreads();
    }

    {   // heads
        const bool is_lv = tid >= 256;
        const int  j  = tid & 63;
        const int  kh = (tid >> 6) & 3;
        const float* Wz = is_lv ? Wlv : Wmu;
        float az = 0.f;
        for (int i = kh * 64; i < kh * 64 + 64; ++i)
            az = fmaf(h2[i], Wz[(size_t)i * DZ + j], az);
        redz[(is_lv ? 4 : 0) + kh][j] = az;
        __syncthreads();
        if (tid < 2 * DZ) {
            const bool lv = tid >= DZ;
            const int  jj = tid & (DZ - 1);
            const int  base = lv ? 4 : 0;
            float rr = redz[base][jj] + redz[base + 1][jj]
                     + redz[base + 2][jj] + redz[base + 3][jj];
            rr += lv ? blv[jj] : bmu[jj];
            out[(lv ? BB * DZ : 0) + (size_t)b * DZ + jj] = rr;
        }
    }
}

extern "C" void kernel_launch(void* const* d_in, const int* in_sizes, int n_in,
                              void* d_out, int out_size, void* d_ws, size_t ws_size,
                              hipStream_t stream) {
    const float* x    = (const float*)d_in[0];
    const int*   gi   = (const int*)  d_in[1];
    const float* emb  = (const float*)d_in[2];
    const float* W1   = (const float*)d_in[3];
    const float* b1   = (const float*)d_in[4];
    const float* W2   = (const float*)d_in[5];
    const float* b2   = (const float*)d_in[6];
    const float* Wmu  = (const float*)d_in[7];
    const float* bmu  = (const float*)d_in[8];
    const float* Wlv  = (const float*)d_in[9];
    const float* blv  = (const float*)d_in[10];
    float* out = (float*)d_out;

    char* ws = (char*)d_ws;
    float* ws_wsum = (float*)(ws + 0);         // <= 1024 entries
    float* ws_xsum = (float*)(ws + 4096);
    const size_t off_main = 8192;

    // full GEMM path sizes
    const size_t szW   = (size_t)BB * KPAD * sizeof(unsigned short);        // 15,368,192
    const size_t szFB  = (size_t)FB_TILES * 1024;                           // 15,368,192
    const size_t szGP  = (size_t)BB * KSPLIT * DG * sizeof(unsigned short); // 16,777,216
    const size_t szP2  = (size_t)BB * NPART2 * DG * sizeof(float);          //  2,097,152
    const size_t need_full = off_main + szW + szFB + szGP + szP2;

    // fallback sizes
    const size_t szPool = (size_t)BB * SPLIT * DG * sizeof(float);
    const size_t szEmbh = (size_t)NGENES * DG * sizeof(unsigned short);
    const size_t need_fb = off_main + szPool + szEmbh;

    if (ws_size >= need_full) {
        unsigned short* Wm    = (unsigned short*)(ws + off_main);
        unsigned short* fragB = (unsigned short*)(ws + off_main + szW);
        unsigned short* wsg16 = (unsigned short*)(ws + off_main + szW + szFB);
        float*          part2 = (float*)(ws + off_main + szW + szFB + szGP);

        scatter_kernel<<<dim3(BB, 2), 256, 0, stream>>>(x, gi, Wm, ws_wsum, ws_xsum);
        fragb_kernel<<<FB_TILES / 4, 256, 0, stream>>>(emb, fragB);
        gemm_kernel<<<dim3(4, KSPLIT), 256, 0, stream>>>(Wm, fragB, wsg16);
        reduce_kernel<<<dim3(BB, NPART2), 256, 0, stream>>>(wsg16, part2);
        mlp_kernel<NPART2, 1><<<BB, 512, 0, stream>>>(part2, ws_wsum, ws_xsum,
                                           W1, b1, W2, b2, Wmu, bmu, Wlv, blv, out);
    } else if (ws_size >= need_fb) {
        float*          ws_pool = (float*)(ws + off_main);
        unsigned short* embh    = (unsigned short*)(ws + off_main + szPool);

        convert_kernel<<<2048, 256, 0, stream>>>(emb, embh, NGENES * DG / 4);
        pool_bf16_kernel<<<dim3(BB, SPLIT), 256, 0, stream>>>(
            x, gi, embh, ws_pool, ws_wsum, ws_xsum);
        mlp_kernel<SPLIT, SPLIT><<<BB, 512, 0, stream>>>(ws_pool, ws_wsum, ws_xsum,
                                           W1, b1, W2, b2, Wmu, bmu, Wlv, blv, out);
    }
}

// Round 8
// 135.816 us; speedup vs baseline: 1.1015x; 1.1015x over previous
//
#include <hip/hip_runtime.h>
#include <math.h>

#define BB      256
#define GG      4096
#define DG      256
#define DH      256
#define DZ      64
#define NGENES  30000
#define KPAD    30016            // NGENES padded to multiple of 32
#define NCHUNK  (KPAD / 32)      // 938 K-chunks of 32
#define KSPLIT  128
#define RED     16               // splits combined per stage-1 reduce block
#define NPART2  (KSPLIT / RED)   // 8
#define HALF    (KPAD / 2)       // 15008
#define FB_TILES (NCHUNK * 16)   // 15008 fragment tiles of 1 KB
#define TSTRIDE 258              // LDS row stride (floats) in fragb: 2-way banks
// fallback (R3) path
#define SPLIT   4
#define GCHUNK  (GG / SPLIT)

typedef __attribute__((ext_vector_type(8))) short  short8v;
typedef __attribute__((ext_vector_type(4))) float  floatx4;

__device__ __forceinline__ unsigned short bf16_rn(float f) {
    unsigned u = __float_as_uint(f);
    u += 0x7FFFu + ((u >> 16) & 1u);   // round-to-nearest-even
    return (unsigned short)(u >> 16);
}

// ---------------------------------------------------------------------------
// Scatter: W16[b, idx] += log1p(x), output bf16.  grid (B, 2).
// ---------------------------------------------------------------------------
__global__ __launch_bounds__(256) void scatter_kernel(
    const float* __restrict__ x,
    const int*   __restrict__ gi,
    unsigned short* __restrict__ W16,  // (BB, KPAD) bf16
    float* __restrict__ wsum,          // (BB)
    float* __restrict__ xsum)          // (BB)
{
    const int b   = blockIdx.x;
    const int h   = blockIdx.y;
    const int tid = threadIdx.x;
    const int base = h * HALF;

    __shared__ float sW[HALF];
    for (int i = tid; i < HALF; i += 256) sW[i] = 0.f;
    __syncthreads();

    const float4* x4 = (const float4*)(x  + (size_t)b * GG);
    const int4*   g4 = (const int4*)  (gi + (size_t)b * GG);

    float lws = 0.f, xs = 0.f;
    #pragma unroll
    for (int it = 0; it < 4; ++it) {
        const int    e  = it * 256 + tid;
        const float4 xv = x4[e];
        const int4   iv = g4[e];
        const float lw0 = log1pf(xv.x), lw1 = log1pf(xv.y);
        const float lw2 = log1pf(xv.z), lw3 = log1pf(xv.w);
        lws += lw0 + lw1 + lw2 + lw3;
        xs  += xv.x + xv.y + xv.z + xv.w;
        int r0 = iv.x - base, r1 = iv.y - base, r2 = iv.z - base, r3 = iv.w - base;
        if ((unsigned)r0 < (unsigned)HALF) atomicAdd(&sW[r0], lw0);
        if ((unsigned)r1 < (unsigned)HALF) atomicAdd(&sW[r1], lw1);
        if ((unsigned)r2 < (unsigned)HALF) atomicAdd(&sW[r2], lw2);
        if ((unsigned)r3 < (unsigned)HALF) atomicAdd(&sW[r3], lw3);
    }
    __syncthreads();

    uint4* dst = (uint4*)(W16 + (size_t)b * KPAD + base);
    for (int i = tid; i < HALF / 8; i += 256) {
        const float* s = &sW[i * 8];
        uint4 o;
        o.x = (unsigned)bf16_rn(s[0]) | ((unsigned)bf16_rn(s[1]) << 16);
        o.y = (unsigned)bf16_rn(s[2]) | ((unsigned)bf16_rn(s[3]) << 16);
        o.z = (unsigned)bf16_rn(s[4]) | ((unsigned)bf16_rn(s[5]) << 16);
        o.w = (unsigned)bf16_rn(s[6]) | ((unsigned)bf16_rn(s[7]) << 16);
        dst[i] = o;
    }
    __syncthreads();   // all reads of sW done; safe to reuse sW[0..7]

    #pragma unroll
    for (int off = 32; off > 0; off >>= 1) {
        lws += __shfl_down(lws, off);
        xs  += __shfl_down(xs,  off);
    }
    if ((tid & 63) == 0) { sW[tid >> 6] = lws; sW[4 + (tid >> 6)] = xs; }
    __syncthreads();
    if (tid == 0 && h == 0) {
        wsum[b] = sW[0] + sW[1] + sW[2] + sW[3];
        xsum[b] = sW[4] + sW[5] + sW[6] + sW[7];
    }
}

// ---------------------------------------------------------------------------
// fragB v2: emb fp32 (NGENES,256) -> bf16 in MFMA B-fragment order.
// One block per K-chunk (32 rows x 256 cols).  Phase 1: fully-coalesced
// float4 global loads -> LDS tile (row stride 258 floats; fragment reads
// then hit 2 lanes/bank = free).  Phase 2: each wave emits 4 fragment
// tiles with one coalesced 16 B store per lane per tile.
// ---------------------------------------------------------------------------
__global__ __launch_bounds__(256) void fragb_kernel(
    const float* __restrict__ emb, unsigned short* __restrict__ fragB)
{
    const int kc   = blockIdx.x;         // 0..NCHUNK-1
    const int tid  = threadIdx.x;
    const int w    = tid >> 6;
    const int lane = tid & 63;
    const int quad = lane >> 4;
    const int l16  = lane & 15;
    const int k0   = kc << 5;

    __shared__ float sT[32 * TSTRIDE];   // ~33 KB

    // phase 1: 8 float4 loads/thread, coalesced; OOB rows (tail chunk) -> 0
    const float4* e4 = (const float4*)emb;
    #pragma unroll
    for (int i = 0; i < 8; ++i) {
        const int f   = i * 256 + tid;   // float4 index in 32x256 tile
        const int row = f >> 6;          // 0..31
        const int col = f & 63;          // float4 col
        float4 v = make_float4(0.f, 0.f, 0.f, 0.f);
        if (k0 + row < NGENES) v = e4[(size_t)(k0 + row) * 64 + col];
        float* d = &sT[row * TSTRIDE + (col << 2)];
        *(float2*)d       = make_float2(v.x, v.y);   // 8B-aligned (1032|8)
        *(float2*)(d + 2) = make_float2(v.z, v.w);
    }
    __syncthreads();

    // phase 2: wave w writes nt = 4w..4w+3
    #pragma unroll
    for (int t = 0; t < 4; ++t) {
        const int nt = (w << 2) + t;
        unsigned short v[8] __attribute__((aligned(16)));
        #pragma unroll
        for (int j = 0; j < 8; ++j)
            v[j] = bf16_rn(sT[(quad * 8 + j) * TSTRIDE + (nt << 4) + l16]);
        *(uint4*)(fragB + (size_t)kc * 8192 + (nt << 9) + lane * 8) = *(const uint4*)v;
    }
}

// ---------------------------------------------------------------------------
// GEMM: h_pool_partial = W16 (256 x KPAD bf16) @ fragB -> bf16 partials.
// 1D grid 512, XCD-swizzled: kslow = bid&7 pins same-ks blocks to one XCD
// so the 4 mt-blocks sharing a B chunk hit the same L2.  R6-proven
// single-buffered 2-barrier K-loop.  Partials: wsg16[(m*KSPLIT+ks)*256+n].
// ---------------------------------------------------------------------------
__global__ __launch_bounds__(256) void gemm_kernel(
    const unsigned short* __restrict__ W16,
    const unsigned short* __restrict__ fragB,
    unsigned short* __restrict__ wsg16)
{
    const int bid  = blockIdx.x;
    const int mt   = (bid >> 3) & 3;
    const int ks   = ((bid >> 5) << 3) | (bid & 7);
    const int tid  = threadIdx.x;
    const int w    = tid >> 6;
    const int lane = tid & 63;
    const int quad = lane >> 4;
    const int l16  = lane & 15;

    const int q = NCHUNK / KSPLIT;           // 7
    const int r = NCHUNK % KSPLIT;           // 42
    const int c0  = ks * q + (ks < r ? ks : r);
    const int cnt = q + (ks < r ? 1 : 0);

    __shared__ short8v sB[1024];             // 16 KB, fragment order

    const unsigned short* Arow =
        W16 + (size_t)((mt << 6) + (w << 4) + l16) * KPAD + (quad << 3);

    floatx4 acc[16];
    #pragma unroll
    for (int nt = 0; nt < 16; ++nt) acc[nt] = (floatx4){0.f, 0.f, 0.f, 0.f};

    for (int c = 0; c < cnt; ++c) {
        const int kc = c0 + c;

        // A fragment: 8 bf16 = one 16 B load
        const short8v af = *(const short8v*)(Arow + ((size_t)kc << 5));

        // stage B chunk (16 KB linear copy, coalesced)
        const uint4* src = (const uint4*)(fragB + (size_t)kc * 8192);
        #pragma unroll
        for (int i = 0; i < 4; ++i)
            ((uint4*)sB)[i * 256 + tid] = src[i * 256 + tid];

        __syncthreads();
        #pragma unroll
        for (int nt = 0; nt < 16; ++nt) {
            const short8v bf = sB[nt * 64 + lane];
            acc[nt] = __builtin_amdgcn_mfma_f32_16x16x32_bf16(af, bf, acc[nt], 0, 0, 0);
        }
        __syncthreads();
    }

    // epilogue: C/D layout col=lane&15, row=quad*4+reg (verified); bf16 out
    #pragma unroll
    for (int nt = 0; nt < 16; ++nt) {
        #pragma unroll
        for (int reg = 0; reg < 4; ++reg) {
            const int m = (mt << 6) + (w << 4) + (quad << 2) + reg;
            const int n = (nt << 4) + l16;
            wsg16[((size_t)m * KSPLIT + ks) * DG + n] = bf16_rn(acc[nt][reg]);
        }
    }
}

// ---------------------------------------------------------------------------
// Stage-1 reduce: 128 bf16 partials -> 8 fp32.  grid (BB, NPART2), 256 thr.
// ---------------------------------------------------------------------------
__global__ __launch_bounds__(256) void reduce_kernel(
    const unsigned short* __restrict__ wsg16, float* __restrict__ part2)
{
    const int b = blockIdx.x, p = blockIdx.y, d = threadIdx.x;
    const unsigned short* src = wsg16 + ((size_t)b * KSPLIT + p * RED) * DG + d;
    float s = 0.f;
    #pragma unroll
    for (int i = 0; i < RED; ++i)
        s += __uint_as_float((unsigned)src[(size_t)i * DG] << 16);
    part2[((size_t)b * NPART2 + p) * DG + d] = s;
}

// ---------------------------------------------------------------------------
// Fallback R3 kernels (used only if ws_size too small for the GEMM path)
// ---------------------------------------------------------------------------
__global__ __launch_bounds__(256) void convert_kernel(
    const float* __restrict__ emb, unsigned short* __restrict__ embh, int n4)
{
    const float4* e4 = (const float4*)emb;
    ushort4*      o4 = (ushort4*)embh;
    const int stride = gridDim.x * 256;
    for (int i = blockIdx.x * 256 + threadIdx.x; i < n4; i += stride) {
        const float4 v = e4[i];
        ushort4 o;
        o.x = bf16_rn(v.x); o.y = bf16_rn(v.y);
        o.z = bf16_rn(v.z); o.w = bf16_rn(v.w);
        o4[i] = o;
    }
}

__global__ __launch_bounds__(256) void pool_bf16_kernel(
    const float*          __restrict__ x,
    const int*            __restrict__ gi,
    const unsigned short* __restrict__ embh,
    float* __restrict__ ws_pool,
    float* __restrict__ ws_wsum,
    float* __restrict__ ws_xsum)
{
    const int b    = blockIdx.x;
    const int s    = blockIdx.y;
    const int tid  = threadIdx.x;
    const int wave = tid >> 6;
    const int lane = tid & 63;

    const float* xrow = x  + (size_t)b * GG + (size_t)s * GCHUNK;
    const int*   irow = gi + (size_t)b * GG + (size_t)s * GCHUNK;
    const uint2* emb2 = (const uint2*)embh;

    __shared__ float lw_s[256];
    __shared__ int   idx_s[256];
    __shared__ float accred[4][256];
    __shared__ float redw[4], redx[4];

    float wsum = 0.f, xsum = 0.f;
    float4 acc = make_float4(0.f, 0.f, 0.f, 0.f);

    for (int g0 = 0; g0 < GCHUNK; g0 += 256) {
        __syncthreads();
        const float xv = xrow[g0 + tid];
        const int   iv = irow[g0 + tid];
        const float lw = log1pf(xv);
        xsum += xv;
        wsum += lw;
        lw_s[tid]  = lw;
        idx_s[tid] = iv;
        __syncthreads();

        #pragma unroll 8
        for (int k = 0; k < 64; ++k) {
            const int   gidx = (k << 2) | wave;
            const float lw_b = lw_s[gidx];
            const uint2 e    = emb2[(size_t)idx_s[gidx] * 64 + lane];
            acc.x = fmaf(lw_b, __uint_as_float(e.x << 16),         acc.x);
            acc.y = fmaf(lw_b, __uint_as_float(e.x & 0xFFFF0000u), acc.y);
            acc.z = fmaf(lw_b, __uint_as_float(e.y << 16),         acc.z);
            acc.w = fmaf(lw_b, __uint_as_float(e.y & 0xFFFF0000u), acc.w);
        }
    }

    accred[wave][lane * 4 + 0] = acc.x;
    accred[wave][lane * 4 + 1] = acc.y;
    accred[wave][lane * 4 + 2] = acc.z;
    accred[wave][lane * 4 + 3] = acc.w;

    #pragma unroll
    for (int off = 32; off > 0; off >>= 1) {
        wsum += __shfl_down(wsum, off);
        xsum += __shfl_down(xsum, off);
    }
    if (lane == 0) { redw[wave] = wsum; redx[wave] = xsum; }
    __syncthreads();

    const float tot = accred[0][tid] + accred[1][tid] + accred[2][tid] + accred[3][tid];
    ws_pool[((size_t)b * SPLIT + s) * DG + tid] = tot;
    if (tid == 0) {
        ws_wsum[b * SPLIT + s] = redw[0] + redw[1] + redw[2] + redw[3];
        ws_xsum[b * SPLIT + s] = redx[0] + redx[1] + redx[2] + redx[3];
    }
}

// ---------------------------------------------------------------------------
// MLP: combine NS partials (compile-time, unrolled) + normalize + 3-layer
// head.  One block (512 thr) per row.
// out: mu (B*64) | logvar (B*64) | h_pool (B*256)
// ---------------------------------------------------------------------------
template <int NS, int NW>
__global__ __launch_bounds__(512) void mlp_kernel(
    const float* __restrict__ part,
    const float* __restrict__ wsA, const float* __restrict__ xsA,
    const float* __restrict__ W1, const float* __restrict__ b1,
    const float* __restrict__ W2, const float* __restrict__ b2,
    const float* __restrict__ Wmu, const float* __restrict__ bmu,
    const float* __restrict__ Wlv, const float* __restrict__ blv,
    float* __restrict__ out)
{
    const int b   = blockIdx.x;
    const int tid = threadIdx.x;
    const int kq  = tid >> 6;
    const int c4  = tid & 63;

    __shared__ float  h[DH + 1];
    __shared__ float  h1[DH];
    __shared__ float  h2[DH];
    __shared__ float4 red[8][64];
    __shared__ float  redz[8][64];

    if (tid < DH) {
        float acc = 0.f;
        #pragma unroll
        for (int s = 0; s < NS; ++s)
            acc += part[((size_t)b * NS + s) * DG + tid];
        float wsum = 0.f, xsum = 0.f;
        #pragma unroll
        for (int s = 0; s < NW; ++s) {
            wsum += wsA[b * NW + s];
            xsum += xsA[b * NW + s];
        }
        const float hp = acc / (wsum + 1e-8f);
        out[2 * BB * DZ + (size_t)b * DG + tid] = hp;
        h[tid] = hp;
        if (tid == 0) h[DH] = log1pf(xsum);
    }
    __syncthreads();

    {   // layer 1: (257) @ W1(257,256), relu
        const float4* Wv = (const float4*)W1;
        float4 a = make_float4(0.f, 0.f, 0.f, 0.f);
        const int i0 = kq * 32;
        const int i1 = i0 + 32 + (kq == 7 ? 1 : 0);
        for (int i = i0; i < i1; ++i) {
            const float  hi = h[i];
            const float4 w  = Wv[(size_t)i * 64 + c4];
            a.x = fmaf(hi, w.x, a.x);
            a.y = fmaf(hi, w.y, a.y);
            a.z = fmaf(hi, w.z, a.z);
            a.w = fmaf(hi, w.w, a.w);
        }
        red[kq][c4] = a;
        __syncthreads();
        if (tid < 64) {
            float4 t = red[0][tid];
            #pragma unroll
            for (int s = 1; s < 8; ++s) {
                const float4 rr = red[s][tid];
                t.x += rr.x; t.y += rr.y; t.z += rr.z; t.w += rr.w;
            }
            const float4 bb = ((const float4*)b1)[tid];
            h1[4 * tid + 0] = fmaxf(t.x + bb.x, 0.f);
            h1[4 * tid + 1] = fmaxf(t.y + bb.y, 0.f);
            h1[4 * tid + 2] = fmaxf(t.z + bb.z, 0.f);
            h1[4 * tid + 3] = fmaxf(t.w + bb.w, 0.f);
        }
        __syncthreads();
    }

    {   // layer 2: (256) @ W2(256,256), relu
        const float4* Wv = (const float4*)W2;
        float4 a = make_float4(0.f, 0.f, 0.f, 0.f);
        const int i0 = kq * 32;
        for (int i = i0; i < i0 + 32; ++i) {
            const float  hi = h1[i];
            const float4 w  = Wv[(size_t)i * 64 + c4];
            a.x = fmaf(hi, w.x, a.x);
            a.y = fmaf(hi, w.y, a.y);
            a.z = fmaf(hi, w.z, a.z);
            a.w = fmaf(hi, w.w, a.w);
        }
        red[kq][c4] = a;
        __syncthreads();
        if (tid < 64) {
            float4 t = red[0][tid];
            #pragma unroll
            for (int s = 1; s < 8; ++s) {
                const float4 rr = red[s][tid];
                t.x += rr.x; t.y += rr.y; t.z += rr.z; t.w += rr.w;
            }
            const float4 bb = ((const float4*)b2)[tid];
            h2[4 * tid + 0] = fmaxf(t.x + bb.x, 0.f);
            h2[4 * tid + 1] = fmaxf(t.y + bb.y, 0.f);
            h2[4 * tid + 2] = fmaxf(t.z + bb.z, 0.f);
            h2[4 * tid + 3] = fmaxf(t.w + bb.w, 0.f);
        }
        __syncthreads();
    }

    {   // heads
        const bool is_lv = tid >= 256;
        const int  j  = tid & 63;
        const int  kh = (tid >> 6) & 3;
        const float* Wz = is_lv ? Wlv : Wmu;
        float az = 0.f;
        for (int i = kh * 64; i < kh * 64 + 64; ++i)
            az = fmaf(h2[i], Wz[(size_t)i * DZ + j], az);
        redz[(is_lv ? 4 : 0) + kh][j] = az;
        __syncthreads();
        if (tid < 2 * DZ) {
            const bool lv = tid >= DZ;
            const int  jj = tid & (DZ - 1);
            const int  base = lv ? 4 : 0;
            float rr = redz[base][jj] + redz[base + 1][jj]
                     + redz[base + 2][jj] + redz[base + 3][jj];
            rr += lv ? blv[jj] : bmu[jj];
            out[(lv ? BB * DZ : 0) + (size_t)b * DZ + jj] = rr;
        }
    }
}

extern "C" void kernel_launch(void* const* d_in, const int* in_sizes, int n_in,
                              void* d_out, int out_size, void* d_ws, size_t ws_size,
                              hipStream_t stream) {
    const float* x    = (const float*)d_in[0];
    const int*   gi   = (const int*)  d_in[1];
    const float* emb  = (const float*)d_in[2];
    const float* W1   = (const float*)d_in[3];
    const float* b1   = (const float*)d_in[4];
    const float* W2   = (const float*)d_in[5];
    const float* b2   = (const float*)d_in[6];
    const float* Wmu  = (const float*)d_in[7];
    const float* bmu  = (const float*)d_in[8];
    const float* Wlv  = (const float*)d_in[9];
    const float* blv  = (const float*)d_in[10];
    float* out = (float*)d_out;

    char* ws = (char*)d_ws;
    float* ws_wsum = (float*)(ws + 0);         // <= 1024 entries
    float* ws_xsum = (float*)(ws + 4096);
    const size_t off_main = 8192;

    // full GEMM path sizes
    const size_t szW   = (size_t)BB * KPAD * sizeof(unsigned short);        // 15,368,192
    const size_t szFB  = (size_t)FB_TILES * 1024;                           // 15,368,192
    const size_t szGP  = (size_t)BB * KSPLIT * DG * sizeof(unsigned short); // 16,777,216
    const size_t szP2  = (size_t)BB * NPART2 * DG * sizeof(float);          //  2,097,152
    const size_t need_full = off_main + szW + szFB + szGP + szP2;

    // fallback sizes
    const size_t szPool = (size_t)BB * SPLIT * DG * sizeof(float);
    const size_t szEmbh = (size_t)NGENES * DG * sizeof(unsigned short);
    const size_t need_fb = off_main + szPool + szEmbh;

    if (ws_size >= need_full) {
        unsigned short* Wm    = (unsigned short*)(ws + off_main);
        unsigned short* fragB = (unsigned short*)(ws + off_main + szW);
        unsigned short* wsg16 = (unsigned short*)(ws + off_main + szW + szFB);
        float*          part2 = (float*)(ws + off_main + szW + szFB + szGP);

        scatter_kernel<<<dim3(BB, 2), 256, 0, stream>>>(x, gi, Wm, ws_wsum, ws_xsum);
        fragb_kernel<<<NCHUNK, 256, 0, stream>>>(emb, fragB);
        gemm_kernel<<<4 * KSPLIT, 256, 0, stream>>>(Wm, fragB, wsg16);
        reduce_kernel<<<dim3(BB, NPART2), 256, 0, stream>>>(wsg16, part2);
        mlp_kernel<NPART2, 1><<<BB, 512, 0, stream>>>(part2, ws_wsum, ws_xsum,
                                           W1, b1, W2, b2, Wmu, bmu, Wlv, blv, out);
    } else if (ws_size >= need_fb) {
        float*          ws_pool = (float*)(ws + off_main);
        unsigned short* embh    = (unsigned short*)(ws + off_main + szPool);

        convert_kernel<<<2048, 256, 0, stream>>>(emb, embh, NGENES * DG / 4);
        pool_bf16_kernel<<<dim3(BB, SPLIT), 256, 0, stream>>>(
            x, gi, embh, ws_pool, ws_wsum, ws_xsum);
        mlp_kernel<SPLIT, SPLIT><<<BB, 512, 0, stream>>>(ws_pool, ws_wsum, ws_xsum,
                                           W1, b1, W2, b2, Wmu, bmu, Wlv, blv, out);
    }
}